// Round 4
// baseline (64.348 us; speedup 1.0000x reference)
//
#include <hip/hip_runtime.h>
#include <math.h>

#define NB 32       // batch
#define NI 32       // input capsules
#define NA 16       // input atoms
#define NOD 10      // output dim
#define NOA 16      // output atoms
#define NK 160      // NOD*NOA
#define NHW 144
#define NROUT 3
#define P 4         // pixels per block (weight L2 traffic ~ 737MB / P)
#define NTHREADS 512
#define SVLD 164    // bf16 row stride: 328B = 82 dwords, 82*i mod 32 spans 16 banks

// manual bf16 RNE pack / unpack
__device__ __forceinline__ unsigned short f2bf(float f) {
    unsigned b = __builtin_bit_cast(unsigned, f);
    b += 0x7fffu + ((b >> 16) & 1u);
    return (unsigned short)(b >> 16);
}
__device__ __forceinline__ float bf2f(unsigned short u) {
    return __builtin_bit_cast(float, (unsigned)u << 16);
}
__device__ __forceinline__ float bf_lo(unsigned d) {
    return __builtin_bit_cast(float, d << 16);
}
__device__ __forceinline__ float bf_hi(unsigned d) {
    return __builtin_bit_cast(float, d & 0xffff0000u);
}

__global__ __launch_bounds__(NTHREADS)
void capsule_routing_kernel(const float* __restrict__ x,      // [B,I,A,HW]
                            const float* __restrict__ weight, // [I,A,K]
                            const float* __restrict__ bias,   // [K]
                            float* __restrict__ out)          // [B,K,HW]
{
    __shared__ float sx[NI][NA][P];                 // 8 KB (f32, float4 rows)
    __shared__ unsigned short sv[P * NI * SVLD];    // 41 KB (bf16 votes)
    __shared__ float slog[P][NI][NOD];              // 5 KB
    __shared__ float srt[P][NI][NOD];               // 5 KB
    __shared__ float sact[P][NOD][NOA];             // 2.5 KB

    const int bk  = blockIdx.x;                     // 0 .. 1151
    const int b   = bk / (NHW / P);                 // HW/P = 36
    const int hw0 = (bk % (NHW / P)) * P;
    const int tid = threadIdx.x;

#define SVIDX(p, i, k) (((p) * NI + (i)) * SVLD + (k))

    // ---- 1) load x slice (float4 over 4 pixels), zero logits ----
    if (tid < NI * NA) {                            // exactly 512
        const int i = tid >> 4;
        const int a = tid & (NA - 1);
        const float4 v = *reinterpret_cast<const float4*>(
            x + (size_t)((b * NI + i) * NA + a) * NHW + hw0);
        *reinterpret_cast<float4*>(&sx[i][a][0]) = v;
    }
    {
        float* lf = &slog[0][0][0];
        for (int j = tid; j < P * NI * NOD; j += NTHREADS) lf[j] = 0.0f;
    }
    __syncthreads();

    // ---- 2) votes: task = (i, k-quad); one weight float4 feeds 4 pixels ----
    for (int j = tid; j < NI * (NK / 4); j += NTHREADS) {   // 1280 tasks
        const int i  = j / (NK / 4);
        const int k0 = (j - i * (NK / 4)) * 4;
        const float4* wp = reinterpret_cast<const float4*>(
            weight + (size_t)i * NA * NK + k0);
        float4 acc[P];
#pragma unroll
        for (int p = 0; p < P; ++p) acc[p] = make_float4(0.f, 0.f, 0.f, 0.f);
#pragma unroll
        for (int a = 0; a < NA; ++a) {
            const float4 w4 = wp[a * (NK / 4)];
            const float4 xa = *reinterpret_cast<const float4*>(&sx[i][a][0]);
            const float xs[P] = {xa.x, xa.y, xa.z, xa.w};
#pragma unroll
            for (int p = 0; p < P; ++p) {
                acc[p].x = fmaf(xs[p], w4.x, acc[p].x);
                acc[p].y = fmaf(xs[p], w4.y, acc[p].y);
                acc[p].z = fmaf(xs[p], w4.z, acc[p].z);
                acc[p].w = fmaf(xs[p], w4.w, acc[p].w);
            }
        }
#pragma unroll
        for (int p = 0; p < P; ++p) {
            ushort4 s = make_ushort4(f2bf(acc[p].x), f2bf(acc[p].y),
                                     f2bf(acc[p].z), f2bf(acc[p].w));
            *reinterpret_cast<ushort4*>(&sv[SVIDX(p, i, k0)]) = s;
        }
    }
    __syncthreads();

    // ---- 3) dynamic routing ----
    for (int it = 0; it < NROUT; ++it) {
        // softmax over od per (p, i): 128 rows
        if (tid < P * NI) {
            const int p = tid >> 5;
            const int i = tid & 31;
            float m = slog[p][i][0];
#pragma unroll
            for (int od = 1; od < NOD; ++od) m = fmaxf(m, slog[p][i][od]);
            float e[NOD];
            float s = 0.0f;
#pragma unroll
            for (int od = 0; od < NOD; ++od) {
                e[od] = __expf(slog[p][i][od] - m);
                s += e[od];
            }
            const float inv = 1.0f / s;
#pragma unroll
            for (int od = 0; od < NOD; ++od) srt[p][i][od] = e[od] * inv;
        }
        __syncthreads();

        // preact + fused squash: 640 tasks (p,k); 16-lane oa-groups stay
        // lane-aligned (160 = 10*16, boundaries at multiples of 16)
        for (int j = tid; j < P * NK; j += NTHREADS) {
            const int p  = j / NK;
            const int k  = j - p * NK;
            const int od = k >> 4;
            const int oa = k & (NOA - 1);
            float acc = bias[k];
            const unsigned short* svp = &sv[SVIDX(p, 0, k)];
#pragma unroll
            for (int i = 0; i < NI; ++i)
                acc = fmaf(srt[p][i][od], bf2f(svp[i * SVLD]), acc);
            float ss = acc * acc;
#pragma unroll
            for (int m = 1; m < NOA; m <<= 1)
                ss += __shfl_xor(ss, m, NOA);
            const float scale = sqrtf(ss) / (1.0f + ss);
            sact[p][od][oa] = acc * scale;
        }
        __syncthreads();

        if (it < NROUT - 1) {
            // logits[p][i][od] += sum_oa votes * act ; uint4 = 8 bf16 per read
            for (int j = tid; j < P * NI * NOD; j += NTHREADS) {  // 1280 tasks
                const int p  = j / (NI * NOD);
                const int r  = j - p * (NI * NOD);
                const int od = r >> 5;
                const int i  = r & 31;
                const uint4 d0 = *reinterpret_cast<const uint4*>(
                    &sv[SVIDX(p, i, od * NOA)]);
                const uint4 d1 = *reinterpret_cast<const uint4*>(
                    &sv[SVIDX(p, i, od * NOA + 8)]);
                const float* ap = &sact[p][od][0];
                float acc;
                acc  = bf_lo(d0.x) * ap[0];
                acc = fmaf(bf_hi(d0.x), ap[1], acc);
                acc = fmaf(bf_lo(d0.y), ap[2], acc);
                acc = fmaf(bf_hi(d0.y), ap[3], acc);
                acc = fmaf(bf_lo(d0.z), ap[4], acc);
                acc = fmaf(bf_hi(d0.z), ap[5], acc);
                acc = fmaf(bf_lo(d0.w), ap[6], acc);
                acc = fmaf(bf_hi(d0.w), ap[7], acc);
                acc = fmaf(bf_lo(d1.x), ap[8], acc);
                acc = fmaf(bf_hi(d1.x), ap[9], acc);
                acc = fmaf(bf_lo(d1.y), ap[10], acc);
                acc = fmaf(bf_hi(d1.y), ap[11], acc);
                acc = fmaf(bf_lo(d1.z), ap[12], acc);
                acc = fmaf(bf_hi(d1.z), ap[13], acc);
                acc = fmaf(bf_lo(d1.w), ap[14], acc);
                acc = fmaf(bf_hi(d1.w), ap[15], acc);
                slog[p][i][od] += acc;
            }
            __syncthreads();
        }
    }

    // ---- 4) write activation: float4 across the 4 pixels ----
    __syncthreads();
    if (tid < NK) {
        const int od = tid >> 4;
        const int oa = tid & (NOA - 1);
        const float4 v = make_float4(sact[0][od][oa], sact[1][od][oa],
                                     sact[2][od][oa], sact[3][od][oa]);
        *reinterpret_cast<float4*>(out + (size_t)(b * NK + tid) * NHW + hw0) = v;
    }
}

extern "C" void kernel_launch(void* const* d_in, const int* in_sizes, int n_in,
                              void* d_out, int out_size, void* d_ws, size_t ws_size,
                              hipStream_t stream) {
    const float* x      = (const float*)d_in[0];
    const float* weight = (const float*)d_in[1];
    const float* bias   = (const float*)d_in[2];
    float* out          = (float*)d_out;

    const int nblocks = NB * (NHW / P);   // 32 * 36 = 1152
    capsule_routing_kernel<<<nblocks, NTHREADS, 0, stream>>>(x, weight, bias, out);
}

// Round 5
// 62.596 us; speedup vs baseline: 1.0280x; 1.0280x over previous
//
#include <hip/hip_runtime.h>
#include <math.h>

#define NB 32
#define NI 32
#define NA 16
#define NOD 10
#define NOA 16
#define NK 160         // NOD*NOA
#define NHW 144
#define NROUT 3
#define NROWS (NB*NHW) // 4608 pixel-rows
#define VOTES_BYTES ((size_t)NI * NROWS * NK * 2)  // 47,185,920 B bf16

// ---- bf16 RNE pack / unpack ----
__device__ __forceinline__ unsigned short f2bf(float f) {
    unsigned b = __builtin_bit_cast(unsigned, f);
    b += 0x7fffu + ((b >> 16) & 1u);
    return (unsigned short)(b >> 16);
}
__device__ __forceinline__ float bf2f(unsigned short u) {
    return __builtin_bit_cast(float, (unsigned)u << 16);
}
__device__ __forceinline__ float bf_lo(unsigned d) {
    return __builtin_bit_cast(float, d << 16);
}
__device__ __forceinline__ float bf_hi(unsigned d) {
    return __builtin_bit_cast(float, d & 0xffff0000u);
}

// =====================================================================
// Kernel 1: votes[i][row][k] = sum_a x[b,i,a,hw] * w[i,a,k]   (bf16 out)
// block = (i, b, hw-half of 72). Weight read once per (i,b,half):
// total weight L2 traffic 2048 * 10KB = 20 MB (vs 737MB/P before).
// =====================================================================
__global__ __launch_bounds__(256)
void votes_kernel(const float* __restrict__ x,        // [B,I,A,HW]
                  const float* __restrict__ weight,   // [I,A,K]
                  unsigned short* __restrict__ votes) // [I,NROWS,K] bf16
{
    __shared__ float sw[NA * NK];   // 10 KB  [a][k]
    __shared__ float sxv[NA * 72];  // 4.6 KB [a][hw_local]

    const int i   = blockIdx.x >> 6;        // /64
    const int b   = (blockIdx.x >> 1) & 31;
    const int hw0 = (blockIdx.x & 1) * 72;
    const int tid = threadIdx.x;

    // load W_i (640 float4, coalesced)
    {
        const float4* src = reinterpret_cast<const float4*>(weight + (size_t)i * NA * NK);
        float4* dst = reinterpret_cast<float4*>(sw);
        for (int j = tid; j < NA * NK / 4; j += 256) dst[j] = src[j];
    }
    // load x slice: 16 rows x 72 f32 (18 float4 each)
    {
        const float* xb = x + ((size_t)(b * NI + i) * NA) * NHW + hw0;
        for (int j = tid; j < NA * 18; j += 256) {
            const int a = j / 18, c = j % 18;
            *reinterpret_cast<float4*>(&sxv[a * 72 + c * 4]) =
                *reinterpret_cast<const float4*>(xb + a * NHW + c * 4);
        }
    }
    __syncthreads();

    // tasks: 72 hw x 40 k-quads; lane map: 16 kq x 4 hw per wave
    //  -> sw float4 read: 16 consecutive kq = 2-way bank alias (free)
    //  -> global store: 4 rows x 128B aligned segments per wave
    unsigned short* vbase = votes + ((size_t)i * NROWS + b * NHW + hw0) * NK;
    for (int t = tid; t < 72 * 40; t += 256) {
        const int kq  = (t >> 2) % 40;
        const int hwl = (t & 3) + ((t / 160) << 2);
        const int k0  = kq * 4;
        float4 acc = make_float4(0.f, 0.f, 0.f, 0.f);
#pragma unroll
        for (int a = 0; a < NA; ++a) {
            const float  xv = sxv[a * 72 + hwl];
            const float4 w4 = *reinterpret_cast<const float4*>(&sw[a * NK + k0]);
            acc.x = fmaf(xv, w4.x, acc.x);
            acc.y = fmaf(xv, w4.y, acc.y);
            acc.z = fmaf(xv, w4.z, acc.z);
            acc.w = fmaf(xv, w4.w, acc.w);
        }
        const ushort4 s = make_ushort4(f2bf(acc.x), f2bf(acc.y), f2bf(acc.z), f2bf(acc.w));
        *reinterpret_cast<ushort4*>(vbase + (size_t)hwl * NK + k0) = s;
    }
}

// =====================================================================
// Kernel 2: dynamic routing. block = P=4 pixel-rows, 512 threads.
// Votes read is a fully-coalesced stream; logits live in registers.
// =====================================================================
#define P 4
#define SVLD 168   // bf16 row stride (336B, 16B-aligned rows)

__global__ __launch_bounds__(512)
void routing_kernel(const unsigned short* __restrict__ votes, // [I,NROWS,K]
                    const float* __restrict__ bias,           // [K]
                    float* __restrict__ out)                  // [B,K,HW]
{
    __shared__ unsigned short sv[P * NI * SVLD];   // 42 KB
    __shared__ float srt[P][NI][NOD];              // 5 KB (route / agreement)
    __shared__ float sact[P][NOD][NOA];            // 2.5 KB

    const int row0 = blockIdx.x * P;   // pixel row base = b*NHW + hw
    const int tid  = threadIdx.x;

    // ---- load votes: 2560 uint4, 5 per thread, contiguous per i ----
    {
        const uint4* src = reinterpret_cast<const uint4*>(votes);
        for (int u = tid; u < NI * P * 20; u += 512) {
            const int i = u / (P * 20);
            const int r = u % (P * 20);
            const int p = r / 20;
            const int c = r % 20;
            *reinterpret_cast<uint4*>(&sv[(p * NI + i) * SVLD + c * 8]) =
                src[(size_t)(i * NROWS + row0 + p) * 20 + c];
        }
    }

    float lg[NOD];   // register logits, owned by tid<128 as (p,i)
#pragma unroll
    for (int od = 0; od < NOD; ++od) lg[od] = 0.f;
    const int pown = tid >> 5;
    const int iown = tid & 31;
    __syncthreads();

    for (int it = 0; it < NROUT; ++it) {
        // softmax over od from register logits (128 owners)
        if (tid < P * NI) {
            float m = lg[0];
#pragma unroll
            for (int od = 1; od < NOD; ++od) m = fmaxf(m, lg[od]);
            float e[NOD];
            float s = 0.f;
#pragma unroll
            for (int od = 0; od < NOD; ++od) {
                e[od] = __expf(lg[od] - m);
                s += e[od];
            }
            const float inv = 1.f / s;
#pragma unroll
            for (int od = 0; od < NOD; ++od) srt[pown][iown][od] = e[od] * inv;
        }
        __syncthreads();

        // preact + fused squash: 640 tasks (p,k), 16-lane oa groups aligned
        for (int j = tid; j < P * NK; j += 512) {
            const int p  = j / NK;
            const int k  = j - p * NK;
            const int od = k >> 4;
            const int oa = k & 15;
            float acc = bias[k];
            const unsigned short* svp = &sv[p * NI * SVLD + k];
#pragma unroll
            for (int i = 0; i < NI; ++i)
                acc = fmaf(srt[p][i][od], bf2f(svp[i * SVLD]), acc);
            float ss = acc * acc;
#pragma unroll
            for (int m = 1; m < NOA; m <<= 1)
                ss += __shfl_xor(ss, m, NOA);
            const float scale = sqrtf(ss) / (1.f + ss);
            sact[p][od][oa] = acc * scale;
        }
        __syncthreads();

        if (it < NROUT - 1) {
            // agreement -> srt (overwrites route, already consumed)
            for (int j = tid; j < P * NI * NOD; j += 512) {
                const int p  = j / (NI * NOD);
                const int r  = j - p * (NI * NOD);
                const int od = r >> 5;
                const int i  = r & 31;
                const uint4 d0 = *reinterpret_cast<const uint4*>(
                    &sv[(p * NI + i) * SVLD + od * NOA]);
                const uint4 d1 = *reinterpret_cast<const uint4*>(
                    &sv[(p * NI + i) * SVLD + od * NOA + 8]);
                const float* ap = &sact[p][od][0];
                float acc;
                acc  = bf_lo(d0.x) * ap[0];
                acc = fmaf(bf_hi(d0.x), ap[1], acc);
                acc = fmaf(bf_lo(d0.y), ap[2], acc);
                acc = fmaf(bf_hi(d0.y), ap[3], acc);
                acc = fmaf(bf_lo(d0.z), ap[4], acc);
                acc = fmaf(bf_hi(d0.z), ap[5], acc);
                acc = fmaf(bf_lo(d0.w), ap[6], acc);
                acc = fmaf(bf_hi(d0.w), ap[7], acc);
                acc = fmaf(bf_lo(d1.x), ap[8], acc);
                acc = fmaf(bf_hi(d1.x), ap[9], acc);
                acc = fmaf(bf_lo(d1.y), ap[10], acc);
                acc = fmaf(bf_hi(d1.y), ap[11], acc);
                acc = fmaf(bf_lo(d1.z), ap[12], acc);
                acc = fmaf(bf_hi(d1.z), ap[13], acc);
                acc = fmaf(bf_lo(d1.w), ap[14], acc);
                acc = fmaf(bf_hi(d1.w), ap[15], acc);
                srt[p][i][od] = acc;
            }
            __syncthreads();
            // owners fold agreement into register logits (own row only:
            // no barrier needed before next softmax writes the same row)
            if (tid < P * NI) {
#pragma unroll
                for (int od = 0; od < NOD; ++od) lg[od] += srt[pown][iown][od];
            }
        }
    }

    // ---- write activation: float4 across 4 pixels ----
    if (tid < NK) {
        const int b  = row0 / NHW;
        const int hw = row0 % NHW;
        const int od = tid >> 4;
        const int oa = tid & 15;
        const float4 v = make_float4(sact[0][od][oa], sact[1][od][oa],
                                     sact[2][od][oa], sact[3][od][oa]);
        *reinterpret_cast<float4*>(out + ((size_t)b * NK + tid) * NHW + hw) = v;
    }
}

// =====================================================================
// Fallback (proven R3 single-kernel, 48us) if workspace is too small.
// =====================================================================
#define FP 2
#define FSVLD 168

__global__ __launch_bounds__(512)
void capsule_fallback_kernel(const float* __restrict__ x,
                             const float* __restrict__ weight,
                             const float* __restrict__ bias,
                             float* __restrict__ out)
{
    __shared__ float sx[NI][NA][FP];
    __shared__ unsigned short sv[FP * NI * FSVLD];
    __shared__ float slog[FP][NI][NOD];
    __shared__ float srt[FP][NI][NOD];
    __shared__ float sact[FP][NOD][NOA];

    const int bk  = blockIdx.x;
    const int b   = bk / (NHW / FP);
    const int hw0 = (bk % (NHW / FP)) * FP;
    const int tid = threadIdx.x;
#define FSVIDX(p, i, k) (((p) * NI + (i)) * FSVLD + (k))

    if (tid < NI * NA) {
        const int i = tid >> 4;
        const int a = tid & (NA - 1);
        const float2 v = *reinterpret_cast<const float2*>(
            x + (size_t)((b * NI + i) * NA + a) * NHW + hw0);
        sx[i][a][0] = v.x;
        sx[i][a][1] = v.y;
    }
    {
        float* lf = &slog[0][0][0];
        for (int j = tid; j < FP * NI * NOD; j += 512) lf[j] = 0.0f;
    }
    __syncthreads();

    for (int j = tid; j < NI * (NK / 4); j += 512) {
        const int i  = j / (NK / 4);
        const int k0 = (j - i * (NK / 4)) * 4;
        const float4* wp = reinterpret_cast<const float4*>(weight + (size_t)i * NA * NK + k0);
        float4 a0 = make_float4(0.f, 0.f, 0.f, 0.f);
        float4 a1 = make_float4(0.f, 0.f, 0.f, 0.f);
#pragma unroll
        for (int a = 0; a < NA; ++a) {
            const float4 w4 = wp[a * (NK / 4)];
            const float2 xa = *reinterpret_cast<const float2*>(&sx[i][a][0]);
            a0.x = fmaf(xa.x, w4.x, a0.x); a0.y = fmaf(xa.x, w4.y, a0.y);
            a0.z = fmaf(xa.x, w4.z, a0.z); a0.w = fmaf(xa.x, w4.w, a0.w);
            a1.x = fmaf(xa.y, w4.x, a1.x); a1.y = fmaf(xa.y, w4.y, a1.y);
            a1.z = fmaf(xa.y, w4.z, a1.z); a1.w = fmaf(xa.y, w4.w, a1.w);
        }
        ushort4 s0 = make_ushort4(f2bf(a0.x), f2bf(a0.y), f2bf(a0.z), f2bf(a0.w));
        ushort4 s1 = make_ushort4(f2bf(a1.x), f2bf(a1.y), f2bf(a1.z), f2bf(a1.w));
        *reinterpret_cast<ushort4*>(&sv[FSVIDX(0, i, k0)]) = s0;
        *reinterpret_cast<ushort4*>(&sv[FSVIDX(1, i, k0)]) = s1;
    }
    __syncthreads();

    for (int it = 0; it < NROUT; ++it) {
        if (tid < FP * NI) {
            const int p = tid >> 5;
            const int i = tid & 31;
            float m = slog[p][i][0];
#pragma unroll
            for (int od = 1; od < NOD; ++od) m = fmaxf(m, slog[p][i][od]);
            float e[NOD];
            float s = 0.0f;
#pragma unroll
            for (int od = 0; od < NOD; ++od) {
                e[od] = __expf(slog[p][i][od] - m);
                s += e[od];
            }
            const float inv = 1.0f / s;
#pragma unroll
            for (int od = 0; od < NOD; ++od) srt[p][i][od] = e[od] * inv;
        }
        __syncthreads();

        if (tid < FP * NK) {
            const int p  = tid / NK;
            const int k  = tid - p * NK;
            const int od = k >> 4;
            const int oa = k & (NOA - 1);
            float acc = bias[k];
            const unsigned short* svp = &sv[FSVIDX(p, 0, k)];
#pragma unroll
            for (int i = 0; i < NI; ++i)
                acc = fmaf(srt[p][i][od], bf2f(svp[i * FSVLD]), acc);
            float ss = acc * acc;
#pragma unroll
            for (int m = 1; m < NOA; m <<= 1)
                ss += __shfl_xor(ss, m, NOA);
            const float scale = sqrtf(ss) / (1.0f + ss);
            sact[p][od][oa] = acc * scale;
        }
        __syncthreads();

        if (it < NROUT - 1) {
            for (int j = tid; j < FP * NI * NOD; j += 512) {
                const int p  = j / (NI * NOD);
                const int r  = j - p * (NI * NOD);
                const int od = r >> 5;
                const int i  = r & 31;
                const uint4 d0 = *reinterpret_cast<const uint4*>(&sv[FSVIDX(p, i, od * NOA)]);
                const uint4 d1 = *reinterpret_cast<const uint4*>(&sv[FSVIDX(p, i, od * NOA + 8)]);
                const float* ap = &sact[p][od][0];
                float acc;
                acc  = bf_lo(d0.x) * ap[0];
                acc = fmaf(bf_hi(d0.x), ap[1], acc);
                acc = fmaf(bf_lo(d0.y), ap[2], acc);
                acc = fmaf(bf_hi(d0.y), ap[3], acc);
                acc = fmaf(bf_lo(d0.z), ap[4], acc);
                acc = fmaf(bf_hi(d0.z), ap[5], acc);
                acc = fmaf(bf_lo(d0.w), ap[6], acc);
                acc = fmaf(bf_hi(d0.w), ap[7], acc);
                acc = fmaf(bf_lo(d1.x), ap[8], acc);
                acc = fmaf(bf_hi(d1.x), ap[9], acc);
                acc = fmaf(bf_lo(d1.y), ap[10], acc);
                acc = fmaf(bf_hi(d1.y), ap[11], acc);
                acc = fmaf(bf_lo(d1.z), ap[12], acc);
                acc = fmaf(bf_hi(d1.z), ap[13], acc);
                acc = fmaf(bf_lo(d1.w), ap[14], acc);
                acc = fmaf(bf_hi(d1.w), ap[15], acc);
                slog[p][i][od] += acc;
            }
            __syncthreads();
        }
    }

    __syncthreads();
    if (tid < NK) {
        const int od = tid >> 4;
        const int oa = tid & (NOA - 1);
        const float2 v = make_float2(sact[0][od][oa], sact[1][od][oa]);
        *reinterpret_cast<float2*>(out + (size_t)(b * NK + tid) * NHW + hw0) = v;
    }
}

extern "C" void kernel_launch(void* const* d_in, const int* in_sizes, int n_in,
                              void* d_out, int out_size, void* d_ws, size_t ws_size,
                              hipStream_t stream) {
    const float* x      = (const float*)d_in[0];
    const float* weight = (const float*)d_in[1];
    const float* bias   = (const float*)d_in[2];
    float* out          = (float*)d_out;

    if (ws_size >= VOTES_BYTES) {
        unsigned short* votes = (unsigned short*)d_ws;
        votes_kernel<<<NI * NB * 2, 256, 0, stream>>>(x, weight, votes);
        routing_kernel<<<NROWS / P, 512, 0, stream>>>(votes, bias, out);
    } else {
        capsule_fallback_kernel<<<NB * (NHW / FP), 512, 0, stream>>>(x, weight, bias, out);
    }
}

// Round 6
// 54.128 us; speedup vs baseline: 1.1888x; 1.1565x over previous
//
#include <hip/hip_runtime.h>
#include <math.h>

#define NB 32
#define NI 32
#define NA 16
#define NOD 10
#define NOA 16
#define NK 160         // NOD*NOA
#define NHW 144
#define NROUT 3
#define NROWS (NB*NHW) // 4608 pixel-rows
#define VOTES_BYTES ((size_t)NI * NROWS * NK * 2)  // 47,185,920 B bf16

// ---- bf16 RNE pack / unpack ----
__device__ __forceinline__ unsigned short f2bf(float f) {
    unsigned b = __builtin_bit_cast(unsigned, f);
    b += 0x7fffu + ((b >> 16) & 1u);
    return (unsigned short)(b >> 16);
}
__device__ __forceinline__ float bf2f(unsigned short u) {
    return __builtin_bit_cast(float, (unsigned)u << 16);
}
__device__ __forceinline__ float bf_lo(unsigned d) {
    return __builtin_bit_cast(float, d << 16);
}
__device__ __forceinline__ float bf_hi(unsigned d) {
    return __builtin_bit_cast(float, d & 0xffff0000u);
}

// =====================================================================
// Kernel 1: votes[i][row][k] = sum_a x[b,i,a,hw] * w[i,a,k]   (bf16 out)
// block = (i, b, hw-half of 72). Weight read from GLOBAL (L2-resident,
// 61KB/block) -- no weight LDS staging (R5's 42us LDS-BW mistake).
// x staged transposed [hw][a] so tasks read x as float4 along a.
// Task = (kq, 12-hw group): 240 tasks, 48 acc registers each.
// =====================================================================
__global__ __launch_bounds__(256)
void votes_kernel(const float* __restrict__ x,        // [B,I,A,HW]
                  const float* __restrict__ weight,   // [I,A,K]
                  unsigned short* __restrict__ votes) // [I,NROWS,K] bf16
{
    __shared__ float sx[72][20];    // [hw_local][a+pad] 5.76 KB

    const int i   = blockIdx.x >> 6;        // /64
    const int b   = (blockIdx.x >> 1) & 31;
    const int hw0 = (blockIdx.x & 1) * 72;
    const int tid = threadIdx.x;

    // load x slice: read float4 along hw (coalesced), write transposed
    {
        const float* xb = x + ((size_t)(b * NI + i) * NA) * NHW + hw0;
        for (int j = tid; j < NA * 18; j += 256) {
            const int a  = j / 18;
            const int hq = j % 18;
            const float4 v = *reinterpret_cast<const float4*>(xb + a * NHW + hq * 4);
            sx[hq * 4 + 0][a] = v.x;
            sx[hq * 4 + 1][a] = v.y;
            sx[hq * 4 + 2][a] = v.z;
            sx[hq * 4 + 3][a] = v.w;
        }
    }
    __syncthreads();

    if (tid < 240) {
        const int kq  = tid % 40;
        const int grp = tid / 40;
        const int k0  = kq * 4;
        const int hwb = grp * 12;
        const float4* wp = reinterpret_cast<const float4*>(
            weight + (size_t)i * NA * NK + k0);   // wp[a*40]

        float acc[48];   // [h][e], constant-indexed (stays in VGPRs)
#pragma unroll
        for (int q = 0; q < 48; ++q) acc[q] = 0.f;

#pragma unroll
        for (int ab = 0; ab < NA; ab += 4) {
            float xr[48];   // x[hwb+h][ab..ab+3]
#pragma unroll
            for (int h = 0; h < 12; ++h) {
                const float4 t = *reinterpret_cast<const float4*>(&sx[hwb + h][ab]);
                xr[h * 4 + 0] = t.x; xr[h * 4 + 1] = t.y;
                xr[h * 4 + 2] = t.z; xr[h * 4 + 3] = t.w;
            }
#pragma unroll
            for (int e = 0; e < 4; ++e) {
                const float4 w4 = wp[(size_t)(ab + e) * 40];
#pragma unroll
                for (int h = 0; h < 12; ++h) {
                    const float xv = xr[h * 4 + e];
                    acc[h * 4 + 0] = fmaf(xv, w4.x, acc[h * 4 + 0]);
                    acc[h * 4 + 1] = fmaf(xv, w4.y, acc[h * 4 + 1]);
                    acc[h * 4 + 2] = fmaf(xv, w4.z, acc[h * 4 + 2]);
                    acc[h * 4 + 3] = fmaf(xv, w4.w, acc[h * 4 + 3]);
                }
            }
        }
        unsigned short* vbase =
            votes + ((size_t)i * NROWS + b * NHW + hw0 + hwb) * NK + k0;
#pragma unroll
        for (int h = 0; h < 12; ++h) {
            const ushort4 s = make_ushort4(f2bf(acc[h * 4 + 0]), f2bf(acc[h * 4 + 1]),
                                           f2bf(acc[h * 4 + 2]), f2bf(acc[h * 4 + 3]));
            *reinterpret_cast<ushort4*>(vbase + (size_t)h * NK) = s;
        }
    }
}

// =====================================================================
// Kernel 2: dynamic routing. P=2 pixels, 320 threads, ~25.4KB LDS
// -> 6 blocks/CU (30/32 waves). preact = 80 k-quad tasks (b64 vote
// reads, conflict-free padded route reads); agreement = 640 tasks
// (uint4 vote + broadcast act reads); logits in wave-0 registers.
// =====================================================================
#define P 2
#define SVLD 168   // bf16 row stride (336B, 16B-aligned)

__global__ __launch_bounds__(320)
void routing_kernel(const unsigned short* __restrict__ votes, // [I,NROWS,K]
                    const float* __restrict__ bias,           // [K]
                    float* __restrict__ out)                  // [B,K,HW]
{
    __shared__ unsigned short sv[P * NI * SVLD];   // 21 KB
    __shared__ float srt[P][NOD][33];              // 2.6 KB route/agreement (pad 33)
    __shared__ float sact[P][NOD][NOA];            // 1.25 KB

    const int row0 = blockIdx.x * P;
    const int tid  = threadIdx.x;

    // ---- load votes: 1280 uint4, 4 per thread, contiguous runs ----
    {
        const uint4* src = reinterpret_cast<const uint4*>(votes);
        for (int u = tid; u < NI * P * 20; u += 320) {
            const int i = u / (P * 20);
            const int r = u % (P * 20);
            const int p = r / 20;
            const int c = r % 20;
            *reinterpret_cast<uint4*>(&sv[(p * NI + i) * SVLD + c * 8]) =
                src[(size_t)(i * NROWS + row0 + p) * 20 + c];
        }
    }

    float lg[NOD];   // register logits, owners = tid<64 as (p=tid>>5, i=tid&31)
#pragma unroll
    for (int od = 0; od < NOD; ++od) lg[od] = 0.f;
    const int pown = tid >> 5;
    const int iown = tid & 31;
    __syncthreads();

    for (int it = 0; it < NROUT; ++it) {
        // ---- softmax over od (64 owner lanes = wave 0) ----
        if (tid < P * NI) {
            float m = lg[0];
#pragma unroll
            for (int od = 1; od < NOD; ++od) m = fmaxf(m, lg[od]);
            float e[NOD];
            float s = 0.f;
#pragma unroll
            for (int od = 0; od < NOD; ++od) {
                e[od] = __expf(lg[od] - m);
                s += e[od];
            }
            const float inv = 1.f / s;
#pragma unroll
            for (int od = 0; od < NOD; ++od) srt[pown][od][iown] = e[od] * inv;
        }
        __syncthreads();

        // ---- preact + fused squash: 80 k-quad tasks ----
        if (tid < P * 40) {
            const int p  = tid / 40;
            const int kq = tid % 40;
            const int k0 = kq * 4;
            const int od = kq >> 2;
            const float4 b4 = *reinterpret_cast<const float4*>(bias + k0);
            float a0 = b4.x, a1 = b4.y, a2 = b4.z, a3 = b4.w;
            const unsigned short* svp = &sv[(p * NI) * SVLD + k0];
#pragma unroll
            for (int i = 0; i < NI; ++i) {
                const uint2 d = *reinterpret_cast<const uint2*>(svp + i * SVLD);
                const float r = srt[p][od][i];
                a0 = fmaf(r, bf_lo(d.x), a0);
                a1 = fmaf(r, bf_hi(d.x), a1);
                a2 = fmaf(r, bf_lo(d.y), a2);
                a3 = fmaf(r, bf_hi(d.y), a3);
            }
            float ss = a0 * a0 + a1 * a1 + a2 * a2 + a3 * a3;
            ss += __shfl_xor(ss, 1, 4);
            ss += __shfl_xor(ss, 2, 4);
            const float scale = sqrtf(ss) / (1.f + ss);
            const float4 o = make_float4(a0 * scale, a1 * scale, a2 * scale, a3 * scale);
            *reinterpret_cast<float4*>(&sact[p][od][(kq & 3) * 4]) = o;
        }
        __syncthreads();

        if (it < NROUT - 1) {
            // ---- agreement: 640 tasks (p,od,i), 2 per thread ----
            for (int t = tid; t < P * NOD * NI; t += 320) {
                const int p  = t / (NOD * NI);
                const int r  = t % (NOD * NI);
                const int od = r / NI;
                const int i  = r % NI;
                const uint4 d0 = *reinterpret_cast<const uint4*>(
                    &sv[(p * NI + i) * SVLD + od * NOA]);
                const uint4 d1 = *reinterpret_cast<const uint4*>(
                    &sv[(p * NI + i) * SVLD + od * NOA + 8]);
                const float4 c0 = *reinterpret_cast<const float4*>(&sact[p][od][0]);
                const float4 c1 = *reinterpret_cast<const float4*>(&sact[p][od][4]);
                const float4 c2 = *reinterpret_cast<const float4*>(&sact[p][od][8]);
                const float4 c3 = *reinterpret_cast<const float4*>(&sact[p][od][12]);
                float acc;
                acc  = bf_lo(d0.x) * c0.x;
                acc = fmaf(bf_hi(d0.x), c0.y, acc);
                acc = fmaf(bf_lo(d0.y), c0.z, acc);
                acc = fmaf(bf_hi(d0.y), c0.w, acc);
                acc = fmaf(bf_lo(d0.z), c1.x, acc);
                acc = fmaf(bf_hi(d0.z), c1.y, acc);
                acc = fmaf(bf_lo(d0.w), c1.z, acc);
                acc = fmaf(bf_hi(d0.w), c1.w, acc);
                acc = fmaf(bf_lo(d1.x), c2.x, acc);
                acc = fmaf(bf_hi(d1.x), c2.y, acc);
                acc = fmaf(bf_lo(d1.y), c2.z, acc);
                acc = fmaf(bf_hi(d1.y), c2.w, acc);
                acc = fmaf(bf_lo(d1.z), c3.x, acc);
                acc = fmaf(bf_hi(d1.z), c3.y, acc);
                acc = fmaf(bf_lo(d1.w), c3.z, acc);
                acc = fmaf(bf_hi(d1.w), c3.w, acc);
                srt[p][od][i] = acc;
            }
            __syncthreads();
            if (tid < P * NI) {
#pragma unroll
                for (int od = 0; od < NOD; ++od) lg[od] += srt[pown][od][iown];
            }
        }
    }

    // ---- write activation: float2 across 2 pixels ----
    if (tid < NK) {
        const int b  = row0 / NHW;
        const int hw = row0 % NHW;
        const int od = tid >> 4;
        const int oa = tid & 15;
        const float2 v = make_float2(sact[0][od][oa], sact[1][od][oa]);
        *reinterpret_cast<float2*>(out + ((size_t)b * NK + tid) * NHW + hw) = v;
    }
}

// =====================================================================
// Fallback (proven R3 single-kernel) if workspace is too small.
// =====================================================================
#define FP 2
#define FSVLD 168

__global__ __launch_bounds__(512)
void capsule_fallback_kernel(const float* __restrict__ x,
                             const float* __restrict__ weight,
                             const float* __restrict__ bias,
                             float* __restrict__ out)
{
    __shared__ float sx[NI][NA][FP];
    __shared__ unsigned short svf[FP * NI * FSVLD];
    __shared__ float slog[FP][NI][NOD];
    __shared__ float srtf[FP][NI][NOD];
    __shared__ float sactf[FP][NOD][NOA];

    const int bk  = blockIdx.x;
    const int b   = bk / (NHW / FP);
    const int hw0 = (bk % (NHW / FP)) * FP;
    const int tid = threadIdx.x;
#define FSVIDX(p, i, k) (((p) * NI + (i)) * FSVLD + (k))

    if (tid < NI * NA) {
        const int i = tid >> 4;
        const int a = tid & (NA - 1);
        const float2 v = *reinterpret_cast<const float2*>(
            x + (size_t)((b * NI + i) * NA + a) * NHW + hw0);
        sx[i][a][0] = v.x;
        sx[i][a][1] = v.y;
    }
    {
        float* lf = &slog[0][0][0];
        for (int j = tid; j < FP * NI * NOD; j += 512) lf[j] = 0.0f;
    }
    __syncthreads();

    for (int j = tid; j < NI * (NK / 4); j += 512) {
        const int i  = j / (NK / 4);
        const int k0 = (j - i * (NK / 4)) * 4;
        const float4* wp = reinterpret_cast<const float4*>(weight + (size_t)i * NA * NK + k0);
        float4 a0 = make_float4(0.f, 0.f, 0.f, 0.f);
        float4 a1 = make_float4(0.f, 0.f, 0.f, 0.f);
#pragma unroll
        for (int a = 0; a < NA; ++a) {
            const float4 w4 = wp[a * (NK / 4)];
            const float2 xa = *reinterpret_cast<const float2*>(&sx[i][a][0]);
            a0.x = fmaf(xa.x, w4.x, a0.x); a0.y = fmaf(xa.x, w4.y, a0.y);
            a0.z = fmaf(xa.x, w4.z, a0.z); a0.w = fmaf(xa.x, w4.w, a0.w);
            a1.x = fmaf(xa.y, w4.x, a1.x); a1.y = fmaf(xa.y, w4.y, a1.y);
            a1.z = fmaf(xa.y, w4.z, a1.z); a1.w = fmaf(xa.y, w4.w, a1.w);
        }
        ushort4 s0 = make_ushort4(f2bf(a0.x), f2bf(a0.y), f2bf(a0.z), f2bf(a0.w));
        ushort4 s1 = make_ushort4(f2bf(a1.x), f2bf(a1.y), f2bf(a1.z), f2bf(a1.w));
        *reinterpret_cast<ushort4*>(&svf[FSVIDX(0, i, k0)]) = s0;
        *reinterpret_cast<ushort4*>(&svf[FSVIDX(1, i, k0)]) = s1;
    }
    __syncthreads();

    for (int it = 0; it < NROUT; ++it) {
        if (tid < FP * NI) {
            const int p = tid >> 5;
            const int i = tid & 31;
            float m = slog[p][i][0];
#pragma unroll
            for (int od = 1; od < NOD; ++od) m = fmaxf(m, slog[p][i][od]);
            float e[NOD];
            float s = 0.0f;
#pragma unroll
            for (int od = 0; od < NOD; ++od) {
                e[od] = __expf(slog[p][i][od] - m);
                s += e[od];
            }
            const float inv = 1.0f / s;
#pragma unroll
            for (int od = 0; od < NOD; ++od) srtf[p][i][od] = e[od] * inv;
        }
        __syncthreads();

        if (tid < FP * NK) {
            const int p  = tid / NK;
            const int k  = tid - p * NK;
            const int od = k >> 4;
            const int oa = k & (NOA - 1);
            float acc = bias[k];
            const unsigned short* svp = &svf[FSVIDX(p, 0, k)];
#pragma unroll
            for (int i = 0; i < NI; ++i)
                acc = fmaf(srtf[p][i][od], bf2f(svp[i * FSVLD]), acc);
            float ss = acc * acc;
#pragma unroll
            for (int m = 1; m < NOA; m <<= 1)
                ss += __shfl_xor(ss, m, NOA);
            const float scale = sqrtf(ss) / (1.0f + ss);
            sactf[p][od][oa] = acc * scale;
        }
        __syncthreads();

        if (it < NROUT - 1) {
            for (int j = tid; j < FP * NI * NOD; j += 512) {
                const int p  = j / (NI * NOD);
                const int r  = j - p * (NI * NOD);
                const int od = r >> 5;
                const int i  = r & 31;
                const uint4 d0 = *reinterpret_cast<const uint4*>(&svf[FSVIDX(p, i, od * NOA)]);
                const uint4 d1 = *reinterpret_cast<const uint4*>(&svf[FSVIDX(p, i, od * NOA + 8)]);
                const float* ap = &sactf[p][od][0];
                float acc;
                acc  = bf_lo(d0.x) * ap[0];
                acc = fmaf(bf_hi(d0.x), ap[1], acc);
                acc = fmaf(bf_lo(d0.y), ap[2], acc);
                acc = fmaf(bf_hi(d0.y), ap[3], acc);
                acc = fmaf(bf_lo(d0.z), ap[4], acc);
                acc = fmaf(bf_hi(d0.z), ap[5], acc);
                acc = fmaf(bf_lo(d0.w), ap[6], acc);
                acc = fmaf(bf_hi(d0.w), ap[7], acc);
                acc = fmaf(bf_lo(d1.x), ap[8], acc);
                acc = fmaf(bf_hi(d1.x), ap[9], acc);
                acc = fmaf(bf_lo(d1.y), ap[10], acc);
                acc = fmaf(bf_hi(d1.y), ap[11], acc);
                acc = fmaf(bf_lo(d1.z), ap[12], acc);
                acc = fmaf(bf_hi(d1.z), ap[13], acc);
                acc = fmaf(bf_lo(d1.w), ap[14], acc);
                acc = fmaf(bf_hi(d1.w), ap[15], acc);
                slog[p][i][od] += acc;
            }
            __syncthreads();
        }
    }

    __syncthreads();
    if (tid < NK) {
        const int od = tid >> 4;
        const int oa = tid & (NOA - 1);
        const float2 v = make_float2(sactf[0][od][oa], sactf[1][od][oa]);
        *reinterpret_cast<float2*>(out + (size_t)(b * NK + tid) * NHW + hw0) = v;
    }
}

extern "C" void kernel_launch(void* const* d_in, const int* in_sizes, int n_in,
                              void* d_out, int out_size, void* d_ws, size_t ws_size,
                              hipStream_t stream) {
    const float* x      = (const float*)d_in[0];
    const float* weight = (const float*)d_in[1];
    const float* bias   = (const float*)d_in[2];
    float* out          = (float*)d_out;

    if (ws_size >= VOTES_BYTES) {
        unsigned short* votes = (unsigned short*)d_ws;
        votes_kernel<<<NI * NB * 2, 256, 0, stream>>>(x, weight, votes);
        routing_kernel<<<NROWS / P, 320, 0, stream>>>(votes, bias, out);
    } else {
        capsule_fallback_kernel<<<NB * (NHW / FP), 512, 0, stream>>>(x, weight, bias, out);
    }
}

// Round 7
// 44.427 us; speedup vs baseline: 1.4484x; 1.2184x over previous
//
#include <hip/hip_runtime.h>
#include <math.h>

#define NB 32
#define NI 32
#define NA 16
#define NOD 10
#define NOA 16
#define NK 160         // NOD*NOA
#define NHW 144
#define NROUT 3
#define NROWS (NB*NHW) // 4608 pixel-rows
#define VOTES_BYTES ((size_t)NI * NROWS * NK * 2)  // 47,185,920 B bf16

// ---- bf16 RNE pack / unpack ----
__device__ __forceinline__ unsigned short f2bf(float f) {
    unsigned b = __builtin_bit_cast(unsigned, f);
    b += 0x7fffu + ((b >> 16) & 1u);
    return (unsigned short)(b >> 16);
}
__device__ __forceinline__ float bf2f(unsigned short u) {
    return __builtin_bit_cast(float, (unsigned)u << 16);
}
__device__ __forceinline__ float bf_lo(unsigned d) {
    return __builtin_bit_cast(float, d << 16);
}
__device__ __forceinline__ float bf_hi(unsigned d) {
    return __builtin_bit_cast(float, d & 0xffff0000u);
}

// =====================================================================
// Kernel 1 (unchanged from R6): votes[i][row][k] = sum_a x * w, bf16 out
// =====================================================================
__global__ __launch_bounds__(256)
void votes_kernel(const float* __restrict__ x,        // [B,I,A,HW]
                  const float* __restrict__ weight,   // [I,A,K]
                  unsigned short* __restrict__ votes) // [I,NROWS,K] bf16
{
    __shared__ float sx[72][20];    // [hw_local][a+pad]

    const int i   = blockIdx.x >> 6;
    const int b   = (blockIdx.x >> 1) & 31;
    const int hw0 = (blockIdx.x & 1) * 72;
    const int tid = threadIdx.x;

    {
        const float* xb = x + ((size_t)(b * NI + i) * NA) * NHW + hw0;
        for (int j = tid; j < NA * 18; j += 256) {
            const int a  = j / 18;
            const int hq = j % 18;
            const float4 v = *reinterpret_cast<const float4*>(xb + a * NHW + hq * 4);
            sx[hq * 4 + 0][a] = v.x;
            sx[hq * 4 + 1][a] = v.y;
            sx[hq * 4 + 2][a] = v.z;
            sx[hq * 4 + 3][a] = v.w;
        }
    }
    __syncthreads();

    if (tid < 240) {
        const int kq  = tid % 40;
        const int grp = tid / 40;
        const int k0  = kq * 4;
        const int hwb = grp * 12;
        const float4* wp = reinterpret_cast<const float4*>(
            weight + (size_t)i * NA * NK + k0);

        float acc[48];
#pragma unroll
        for (int q = 0; q < 48; ++q) acc[q] = 0.f;

#pragma unroll
        for (int ab = 0; ab < NA; ab += 4) {
            float xr[48];
#pragma unroll
            for (int h = 0; h < 12; ++h) {
                const float4 t = *reinterpret_cast<const float4*>(&sx[hwb + h][ab]);
                xr[h * 4 + 0] = t.x; xr[h * 4 + 1] = t.y;
                xr[h * 4 + 2] = t.z; xr[h * 4 + 3] = t.w;
            }
#pragma unroll
            for (int e = 0; e < 4; ++e) {
                const float4 w4 = wp[(size_t)(ab + e) * 40];
#pragma unroll
                for (int h = 0; h < 12; ++h) {
                    const float xv = xr[h * 4 + e];
                    acc[h * 4 + 0] = fmaf(xv, w4.x, acc[h * 4 + 0]);
                    acc[h * 4 + 1] = fmaf(xv, w4.y, acc[h * 4 + 1]);
                    acc[h * 4 + 2] = fmaf(xv, w4.z, acc[h * 4 + 2]);
                    acc[h * 4 + 3] = fmaf(xv, w4.w, acc[h * 4 + 3]);
                }
            }
        }
        unsigned short* vbase =
            votes + ((size_t)i * NROWS + b * NHW + hw0 + hwb) * NK + k0;
#pragma unroll
        for (int h = 0; h < 12; ++h) {
            const ushort4 s = make_ushort4(f2bf(acc[h * 4 + 0]), f2bf(acc[h * 4 + 1]),
                                           f2bf(acc[h * 4 + 2]), f2bf(acc[h * 4 + 3]));
            *reinterpret_cast<ushort4*>(vbase + (size_t)h * NK) = s;
        }
    }
}

// =====================================================================
// Kernel 2: wave-synchronous routing. Block = 256 threads = 4 waves,
// wave w owns pixel-row (blockIdx*4 + w). No __syncthreads in the
// routing loop -- all comms are wave-local LDS slices + wave_barrier.
// Lane map: preact = k-pair (k0=2l, +rep at 128+2l for l<16);
// agreement = 5 reps of (i=t&31, od=t>>5); softmax duplicated halves.
// =====================================================================
#define SVLD 168   // ushort row stride (336 B, uint4-aligned)

__global__ __launch_bounds__(256)
void routing_kernel(const unsigned short* __restrict__ votes, // [I,NROWS,K]
                    const float* __restrict__ bias,           // [K]
                    float* __restrict__ out)                  // [B,K,HW]
{
    __shared__ unsigned short sv[4][NI][SVLD];  // 43 KB votes (bf16)
    __shared__ float srt[4][NOD][33];           // 5.3 KB route / agreement
    __shared__ float sact[4][164];              // 2.6 KB activation (f32)

    const int tid = threadIdx.x;
    const int w   = tid >> 6;          // wave id = local row
    const int l   = tid & 63;          // lane
    const int row = blockIdx.x * 4 + w;

    // ---- load own row's votes: 640 uint4 per row, 10 per lane ----
    {
        const uint4* src = reinterpret_cast<const uint4*>(votes);
#pragma unroll
        for (int r = 0; r < 10; ++r) {
            const int idx = l + 64 * r;        // 0..639
            const int i   = idx / 20;
            const int c   = idx % 20;
            *reinterpret_cast<uint4*>(&sv[w][i][c * 8]) =
                src[((size_t)i * NROWS + row) * 20 + c];
        }
    }

    // bias held in registers (pair layout matches preact lane map)
    const float2 b0 = *reinterpret_cast<const float2*>(bias + 2 * l);
    float2 b1 = make_float2(0.f, 0.f);
    if (l < 16) b1 = *reinterpret_cast<const float2*>(bias + 128 + 2 * l);

    float lg[NOD];
#pragma unroll
    for (int od = 0; od < NOD; ++od) lg[od] = 0.f;
    const int iown = l & 31;

    __builtin_amdgcn_wave_barrier();   // sv ready (same-wave writes)

    for (int it = 0; it < NROUT; ++it) {
        // ---- softmax over od (computed redundantly on both halves) ----
        {
            float m = lg[0];
#pragma unroll
            for (int od = 1; od < NOD; ++od) m = fmaxf(m, lg[od]);
            float e[NOD];
            float s = 0.f;
#pragma unroll
            for (int od = 0; od < NOD; ++od) {
                e[od] = __expf(lg[od] - m);
                s += e[od];
            }
            const float inv = 1.f / s;
            if (l < 32) {
#pragma unroll
                for (int od = 0; od < NOD; ++od) srt[w][od][iown] = e[od] * inv;
            }
        }
        __builtin_amdgcn_wave_barrier();

        // ---- preact + squash: k-pair per lane ----
        {
            // rep0: k0 = 2l (all lanes), od = l>>3
            const int od0 = l >> 3;
            float a0 = b0.x, a1 = b0.y;
#pragma unroll
            for (int i = 0; i < NI; ++i) {
                const unsigned d = *reinterpret_cast<const unsigned*>(&sv[w][i][2 * l]);
                const float r = srt[w][od0][i];
                a0 = fmaf(r, bf_lo(d), a0);
                a1 = fmaf(r, bf_hi(d), a1);
            }
            float ss = a0 * a0 + a1 * a1;
            ss += __shfl_xor(ss, 1, 8);
            ss += __shfl_xor(ss, 2, 8);
            ss += __shfl_xor(ss, 4, 8);
            const float sc = sqrtf(ss) / (1.f + ss);
            *reinterpret_cast<float2*>(&sact[w][2 * l]) = make_float2(a0 * sc, a1 * sc);

            // rep1: k0 = 128 + 2l (lanes 0..15), od = 8 + (l>>3)
            if (l < 16) {
                const int od1 = 8 + (l >> 3);
                float c0 = b1.x, c1 = b1.y;
#pragma unroll
                for (int i = 0; i < NI; ++i) {
                    const unsigned d = *reinterpret_cast<const unsigned*>(&sv[w][i][128 + 2 * l]);
                    const float r = srt[w][od1][i];
                    c0 = fmaf(r, bf_lo(d), c0);
                    c1 = fmaf(r, bf_hi(d), c1);
                }
                float s2 = c0 * c0 + c1 * c1;
                s2 += __shfl_xor(s2, 1, 8);
                s2 += __shfl_xor(s2, 2, 8);
                s2 += __shfl_xor(s2, 4, 8);
                const float sc2 = sqrtf(s2) / (1.f + s2);
                *reinterpret_cast<float2*>(&sact[w][128 + 2 * l]) =
                    make_float2(c0 * sc2, c1 * sc2);
            }
        }
        __builtin_amdgcn_wave_barrier();

        if (it < NROUT - 1) {
            // ---- agreement: 320 (i,od) tasks, 5 per lane ----
#pragma unroll
            for (int r = 0; r < 5; ++r) {
                const int t  = l + 64 * r;
                const int i  = t & 31;
                const int od = t >> 5;
                const uint4 d0 = *reinterpret_cast<const uint4*>(&sv[w][i][od * NOA]);
                const uint4 d1 = *reinterpret_cast<const uint4*>(&sv[w][i][od * NOA + 8]);
                const float4 c0 = *reinterpret_cast<const float4*>(&sact[w][od * NOA + 0]);
                const float4 c1 = *reinterpret_cast<const float4*>(&sact[w][od * NOA + 4]);
                const float4 c2 = *reinterpret_cast<const float4*>(&sact[w][od * NOA + 8]);
                const float4 c3 = *reinterpret_cast<const float4*>(&sact[w][od * NOA + 12]);
                float acc;
                acc  = bf_lo(d0.x) * c0.x;
                acc = fmaf(bf_hi(d0.x), c0.y, acc);
                acc = fmaf(bf_lo(d0.y), c0.z, acc);
                acc = fmaf(bf_hi(d0.y), c0.w, acc);
                acc = fmaf(bf_lo(d0.z), c1.x, acc);
                acc = fmaf(bf_hi(d0.z), c1.y, acc);
                acc = fmaf(bf_lo(d0.w), c1.z, acc);
                acc = fmaf(bf_hi(d0.w), c1.w, acc);
                acc = fmaf(bf_lo(d1.x), c2.x, acc);
                acc = fmaf(bf_hi(d1.x), c2.y, acc);
                acc = fmaf(bf_lo(d1.y), c2.z, acc);
                acc = fmaf(bf_hi(d1.y), c2.w, acc);
                acc = fmaf(bf_lo(d1.z), c3.x, acc);
                acc = fmaf(bf_hi(d1.z), c3.y, acc);
                acc = fmaf(bf_lo(d1.w), c3.z, acc);
                acc = fmaf(bf_hi(d1.w), c3.w, acc);
                srt[w][od][i] = acc;
            }
            __builtin_amdgcn_wave_barrier();
            // fold agreement into register logits (both halves read same)
#pragma unroll
            for (int od = 0; od < NOD; ++od) lg[od] += srt[w][od][iown];
            __builtin_amdgcn_wave_barrier();
        }
    }

    // ---- cross-wave output write: float4 over 4 consecutive pixels ----
    __syncthreads();
    if (tid < NK) {
        const int b  = row / NHW - (w ? (row / NHW) - (blockIdx.x * 4) / NHW : 0); // unused guard
        const int bb = (blockIdx.x * 4) / NHW;
        const int hw = (blockIdx.x * 4) % NHW;
        const float4 v = make_float4(sact[0][tid], sact[1][tid],
                                     sact[2][tid], sact[3][tid]);
        *reinterpret_cast<float4*>(out + ((size_t)bb * NK + tid) * NHW + hw) = v;
    }
}

// =====================================================================
// Fallback (proven R3 single-kernel) if workspace is too small.
// =====================================================================
#define FP 2
#define FSVLD 168

__global__ __launch_bounds__(512)
void capsule_fallback_kernel(const float* __restrict__ x,
                             const float* __restrict__ weight,
                             const float* __restrict__ bias,
                             float* __restrict__ out)
{
    __shared__ float sx[NI][NA][FP];
    __shared__ unsigned short svf[FP * NI * FSVLD];
    __shared__ float slog[FP][NI][NOD];
    __shared__ float srtf[FP][NI][NOD];
    __shared__ float sactf[FP][NOD][NOA];

    const int bk  = blockIdx.x;
    const int b   = bk / (NHW / FP);
    const int hw0 = (bk % (NHW / FP)) * FP;
    const int tid = threadIdx.x;
#define FSVIDX(p, i, k) (((p) * NI + (i)) * FSVLD + (k))

    if (tid < NI * NA) {
        const int i = tid >> 4;
        const int a = tid & (NA - 1);
        const float2 v = *reinterpret_cast<const float2*>(
            x + (size_t)((b * NI + i) * NA + a) * NHW + hw0);
        sx[i][a][0] = v.x;
        sx[i][a][1] = v.y;
    }
    {
        float* lf = &slog[0][0][0];
        for (int j = tid; j < FP * NI * NOD; j += 512) lf[j] = 0.0f;
    }
    __syncthreads();

    for (int j = tid; j < NI * (NK / 4); j += 512) {
        const int i  = j / (NK / 4);
        const int k0 = (j - i * (NK / 4)) * 4;
        const float4* wp = reinterpret_cast<const float4*>(weight + (size_t)i * NA * NK + k0);
        float4 a0 = make_float4(0.f, 0.f, 0.f, 0.f);
        float4 a1 = make_float4(0.f, 0.f, 0.f, 0.f);
#pragma unroll
        for (int a = 0; a < NA; ++a) {
            const float4 w4 = wp[a * (NK / 4)];
            const float2 xa = *reinterpret_cast<const float2*>(&sx[i][a][0]);
            a0.x = fmaf(xa.x, w4.x, a0.x); a0.y = fmaf(xa.x, w4.y, a0.y);
            a0.z = fmaf(xa.x, w4.z, a0.z); a0.w = fmaf(xa.x, w4.w, a0.w);
            a1.x = fmaf(xa.y, w4.x, a1.x); a1.y = fmaf(xa.y, w4.y, a1.y);
            a1.z = fmaf(xa.y, w4.z, a1.z); a1.w = fmaf(xa.y, w4.w, a1.w);
        }
        ushort4 s0 = make_ushort4(f2bf(a0.x), f2bf(a0.y), f2bf(a0.z), f2bf(a0.w));
        ushort4 s1 = make_ushort4(f2bf(a1.x), f2bf(a1.y), f2bf(a1.z), f2bf(a1.w));
        *reinterpret_cast<ushort4*>(&svf[FSVIDX(0, i, k0)]) = s0;
        *reinterpret_cast<ushort4*>(&svf[FSVIDX(1, i, k0)]) = s1;
    }
    __syncthreads();

    for (int it = 0; it < NROUT; ++it) {
        if (tid < FP * NI) {
            const int p = tid >> 5;
            const int i = tid & 31;
            float m = slog[p][i][0];
#pragma unroll
            for (int od = 1; od < NOD; ++od) m = fmaxf(m, slog[p][i][od]);
            float e[NOD];
            float s = 0.0f;
#pragma unroll
            for (int od = 0; od < NOD; ++od) {
                e[od] = __expf(slog[p][i][od] - m);
                s += e[od];
            }
            const float inv = 1.0f / s;
#pragma unroll
            for (int od = 0; od < NOD; ++od) srtf[p][i][od] = e[od] * inv;
        }
        __syncthreads();

        if (tid < FP * NK) {
            const int p  = tid / NK;
            const int k  = tid - p * NK;
            const int od = k >> 4;
            const int oa = k & (NOA - 1);
            float acc = bias[k];
            const unsigned short* svp = &svf[FSVIDX(p, 0, k)];
#pragma unroll
            for (int i = 0; i < NI; ++i)
                acc = fmaf(srtf[p][i][od], bf2f(svp[i * FSVLD]), acc);
            float ss = acc * acc;
#pragma unroll
            for (int m = 1; m < NOA; m <<= 1)
                ss += __shfl_xor(ss, m, NOA);
            const float scale = sqrtf(ss) / (1.0f + ss);
            sactf[p][od][oa] = acc * scale;
        }
        __syncthreads();

        if (it < NROUT - 1) {
            for (int j = tid; j < FP * NI * NOD; j += 512) {
                const int p  = j / (NI * NOD);
                const int r  = j - p * (NI * NOD);
                const int od = r >> 5;
                const int i  = r & 31;
                const uint4 d0 = *reinterpret_cast<const uint4*>(&svf[FSVIDX(p, i, od * NOA)]);
                const uint4 d1 = *reinterpret_cast<const uint4*>(&svf[FSVIDX(p, i, od * NOA + 8)]);
                const float* ap = &sactf[p][od][0];
                float acc;
                acc  = bf_lo(d0.x) * ap[0];
                acc = fmaf(bf_hi(d0.x), ap[1], acc);
                acc = fmaf(bf_lo(d0.y), ap[2], acc);
                acc = fmaf(bf_hi(d0.y), ap[3], acc);
                acc = fmaf(bf_lo(d0.z), ap[4], acc);
                acc = fmaf(bf_hi(d0.z), ap[5], acc);
                acc = fmaf(bf_lo(d0.w), ap[6], acc);
                acc = fmaf(bf_hi(d0.w), ap[7], acc);
                acc = fmaf(bf_lo(d1.x), ap[8], acc);
                acc = fmaf(bf_hi(d1.x), ap[9], acc);
                acc = fmaf(bf_lo(d1.y), ap[10], acc);
                acc = fmaf(bf_hi(d1.y), ap[11], acc);
                acc = fmaf(bf_lo(d1.z), ap[12], acc);
                acc = fmaf(bf_hi(d1.z), ap[13], acc);
                acc = fmaf(bf_lo(d1.w), ap[14], acc);
                acc = fmaf(bf_hi(d1.w), ap[15], acc);
                slog[p][i][od] += acc;
            }
            __syncthreads();
        }
    }

    __syncthreads();
    if (tid < NK) {
        const int od = tid >> 4;
        const int oa = tid & (NOA - 1);
        const float2 v = make_float2(sactf[0][od][oa], sactf[1][od][oa]);
        *reinterpret_cast<float2*>(out + (size_t)(b * NK + tid) * NHW + hw0) = v;
    }
}

extern "C" void kernel_launch(void* const* d_in, const int* in_sizes, int n_in,
                              void* d_out, int out_size, void* d_ws, size_t ws_size,
                              hipStream_t stream) {
    const float* x      = (const float*)d_in[0];
    const float* weight = (const float*)d_in[1];
    const float* bias   = (const float*)d_in[2];
    float* out          = (float*)d_out;

    if (ws_size >= VOTES_BYTES) {
        unsigned short* votes = (unsigned short*)d_ws;
        votes_kernel<<<NI * NB * 2, 256, 0, stream>>>(x, weight, votes);
        routing_kernel<<<NROWS / 4, 256, 0, stream>>>(votes, bias, out);
    } else {
        capsule_fallback_kernel<<<NB * (NHW / FP), 512, 0, stream>>>(x, weight, bias, out);
    }
}

// Round 8
// 43.543 us; speedup vs baseline: 1.4778x; 1.0203x over previous
//
#include <hip/hip_runtime.h>
#include <math.h>

#define NB 32
#define NI 32
#define NA 16
#define NOD 10
#define NOA 16
#define NK 160         // NOD*NOA
#define NHW 144
#define NROUT 3
#define NROWS (NB*NHW) // 4608 pixel-rows
#define SVLD 168       // ushort row stride (336 B, uint4-aligned, bank-spread)

// ---- bf16 RNE pack / unpack ----
__device__ __forceinline__ unsigned short f2bf(float f) {
    unsigned b = __builtin_bit_cast(unsigned, f);
    b += 0x7fffu + ((b >> 16) & 1u);
    return (unsigned short)(b >> 16);
}
__device__ __forceinline__ float bf_lo(unsigned d) {
    return __builtin_bit_cast(float, d << 16);
}
__device__ __forceinline__ float bf_hi(unsigned d) {
    return __builtin_bit_cast(float, d & 0xffff0000u);
}

// =====================================================================
// Fused capsule kernel. Block = 256 threads = 4 waves = 4 pixel-rows.
//  Phase 1 (block-cooperative): votes for all 4 rows; weight float4
//    read ONCE per block (320KB, L2-resident), x staged in LDS pool.
//  Phase 2 (wave-synchronous): wave w owns row w; routing uses only
//    wave_barriers (no __syncthreads) -- proven structure from R7.
//  LDS: sv 43KB + 8KB pool (x-staging UNION srt/sact) = 51.2KB
//    -> 3 blocks/CU (the R4 fused attempt died at 2 blocks/CU).
// =====================================================================
__global__ __launch_bounds__(256)
void capsule_fused_kernel(const float* __restrict__ x,      // [B,I,A,HW]
                          const float* __restrict__ weight, // [I,A,K]
                          const float* __restrict__ bias,   // [K]
                          float* __restrict__ out)          // [B,K,HW]
{
    __shared__ unsigned short sv[4][NI][SVLD];      // 43 KB bf16 votes
    __shared__ __align__(16) float pool[2048];      // 8 KB: sx | srt+sact
    // votes phase:   sx[i][a][p]   = pool[((i*NA)+a)*4 + p]
    // routing phase: srt[w][od][i] = pool[(w*NOD+od)*33 + i]     (1320 f)
    //                sact[w][k]    = pool[1320 + w*164 + k]      ( 656 f)
    float* const srt_f  = pool;
    float* const sact_f = pool + 4 * NOD * 33;

    const int tid  = threadIdx.x;
    const int w    = tid >> 6;            // wave id = local row
    const int l    = tid & 63;            // lane
    const int b    = blockIdx.x / (NHW / 4);
    const int hw0  = (blockIdx.x % (NHW / 4)) * 4;

    // ---- phase 1a: stage x transposed-by-pixel: sx[i][a][0..3] ----
    {
        const float* xb = x + ((size_t)b * NI * NA) * NHW + hw0;
        for (int j = tid; j < NI * NA; j += 256) {       // 2 per thread
            const float4 v = *reinterpret_cast<const float4*>(xb + (size_t)j * NHW);
            *reinterpret_cast<float4*>(&pool[j * 4]) = v;   // j = i*NA+a
        }
    }
    __syncthreads();

    // ---- phase 1b: votes. task=(i,kq): one w4 feeds 4 rows ----
    for (int j = tid; j < NI * 40; j += 256) {           // 5 tasks/thread
        const int i  = j / 40;
        const int kq = j - i * 40;
        const int k0 = kq * 4;
        const float4* wp = reinterpret_cast<const float4*>(
            weight + (size_t)i * NA * NK + k0);
        float4 a0 = make_float4(0.f, 0.f, 0.f, 0.f);
        float4 a1 = make_float4(0.f, 0.f, 0.f, 0.f);
        float4 a2 = make_float4(0.f, 0.f, 0.f, 0.f);
        float4 a3 = make_float4(0.f, 0.f, 0.f, 0.f);
#pragma unroll
        for (int a = 0; a < NA; ++a) {
            const float4 w4 = wp[(size_t)a * 40];
            const float4 xa = *reinterpret_cast<const float4*>(&pool[(i * NA + a) * 4]);
            a0.x = fmaf(xa.x, w4.x, a0.x); a0.y = fmaf(xa.x, w4.y, a0.y);
            a0.z = fmaf(xa.x, w4.z, a0.z); a0.w = fmaf(xa.x, w4.w, a0.w);
            a1.x = fmaf(xa.y, w4.x, a1.x); a1.y = fmaf(xa.y, w4.y, a1.y);
            a1.z = fmaf(xa.y, w4.z, a1.z); a1.w = fmaf(xa.y, w4.w, a1.w);
            a2.x = fmaf(xa.z, w4.x, a2.x); a2.y = fmaf(xa.z, w4.y, a2.y);
            a2.z = fmaf(xa.z, w4.z, a2.z); a2.w = fmaf(xa.z, w4.w, a2.w);
            a3.x = fmaf(xa.w, w4.x, a3.x); a3.y = fmaf(xa.w, w4.y, a3.y);
            a3.z = fmaf(xa.w, w4.z, a3.z); a3.w = fmaf(xa.w, w4.w, a3.w);
        }
        *reinterpret_cast<ushort4*>(&sv[0][i][k0]) =
            make_ushort4(f2bf(a0.x), f2bf(a0.y), f2bf(a0.z), f2bf(a0.w));
        *reinterpret_cast<ushort4*>(&sv[1][i][k0]) =
            make_ushort4(f2bf(a1.x), f2bf(a1.y), f2bf(a1.z), f2bf(a1.w));
        *reinterpret_cast<ushort4*>(&sv[2][i][k0]) =
            make_ushort4(f2bf(a2.x), f2bf(a2.y), f2bf(a2.z), f2bf(a2.w));
        *reinterpret_cast<ushort4*>(&sv[3][i][k0]) =
            make_ushort4(f2bf(a3.x), f2bf(a3.y), f2bf(a3.z), f2bf(a3.w));
    }

    // bias in registers (pair layout matches preact lane map)
    const float2 b0 = *reinterpret_cast<const float2*>(bias + 2 * l);
    float2 b1 = make_float2(0.f, 0.f);
    if (l < 16) b1 = *reinterpret_cast<const float2*>(bias + 128 + 2 * l);

    float lg[NOD];
#pragma unroll
    for (int od = 0; od < NOD; ++od) lg[od] = 0.f;
    const int iown = l & 31;

    __syncthreads();   // sv complete (cross-wave); pool free for srt/sact

    // ---- phase 2: wave-synchronous routing (R7 structure) ----
    for (int it = 0; it < NROUT; ++it) {
        // softmax over od (computed redundantly on both lane-halves)
        {
            float m = lg[0];
#pragma unroll
            for (int od = 1; od < NOD; ++od) m = fmaxf(m, lg[od]);
            float e[NOD];
            float s = 0.f;
#pragma unroll
            for (int od = 0; od < NOD; ++od) {
                e[od] = __expf(lg[od] - m);
                s += e[od];
            }
            const float inv = 1.f / s;
            if (l < 32) {
#pragma unroll
                for (int od = 0; od < NOD; ++od)
                    srt_f[(w * NOD + od) * 33 + iown] = e[od] * inv;
            }
        }
        __builtin_amdgcn_wave_barrier();

        // preact + squash: k-pair per lane
        {
            const int od0 = l >> 3;                  // rep0: k0 = 2l
            float a0 = b0.x, a1 = b0.y;
#pragma unroll
            for (int i = 0; i < NI; ++i) {
                const unsigned d = *reinterpret_cast<const unsigned*>(&sv[w][i][2 * l]);
                const float r = srt_f[(w * NOD + od0) * 33 + i];
                a0 = fmaf(r, bf_lo(d), a0);
                a1 = fmaf(r, bf_hi(d), a1);
            }
            float ss = a0 * a0 + a1 * a1;
            ss += __shfl_xor(ss, 1, 8);
            ss += __shfl_xor(ss, 2, 8);
            ss += __shfl_xor(ss, 4, 8);
            const float sc = sqrtf(ss) / (1.f + ss);
            *reinterpret_cast<float2*>(&sact_f[w * 164 + 2 * l]) =
                make_float2(a0 * sc, a1 * sc);

            if (l < 16) {                            // rep1: k0 = 128 + 2l
                const int od1 = 8 + (l >> 3);
                float c0 = b1.x, c1 = b1.y;
#pragma unroll
                for (int i = 0; i < NI; ++i) {
                    const unsigned d = *reinterpret_cast<const unsigned*>(&sv[w][i][128 + 2 * l]);
                    const float r = srt_f[(w * NOD + od1) * 33 + i];
                    c0 = fmaf(r, bf_lo(d), c0);
                    c1 = fmaf(r, bf_hi(d), c1);
                }
                float s2 = c0 * c0 + c1 * c1;
                s2 += __shfl_xor(s2, 1, 8);
                s2 += __shfl_xor(s2, 2, 8);
                s2 += __shfl_xor(s2, 4, 8);
                const float sc2 = sqrtf(s2) / (1.f + s2);
                *reinterpret_cast<float2*>(&sact_f[w * 164 + 128 + 2 * l]) =
                    make_float2(c0 * sc2, c1 * sc2);
            }
        }
        __builtin_amdgcn_wave_barrier();

        if (it < NROUT - 1) {
            // agreement: 320 (i,od) tasks, 5 per lane
#pragma unroll
            for (int r = 0; r < 5; ++r) {
                const int t  = l + 64 * r;
                const int i  = t & 31;
                const int od = t >> 5;
                const uint4 d0 = *reinterpret_cast<const uint4*>(&sv[w][i][od * NOA]);
                const uint4 d1 = *reinterpret_cast<const uint4*>(&sv[w][i][od * NOA + 8]);
                const float* ap = &sact_f[w * 164 + od * NOA];
                const float4 c0 = *reinterpret_cast<const float4*>(ap + 0);
                const float4 c1 = *reinterpret_cast<const float4*>(ap + 4);
                const float4 c2 = *reinterpret_cast<const float4*>(ap + 8);
                const float4 c3 = *reinterpret_cast<const float4*>(ap + 12);
                float acc;
                acc  = bf_lo(d0.x) * c0.x;
                acc = fmaf(bf_hi(d0.x), c0.y, acc);
                acc = fmaf(bf_lo(d0.y), c0.z, acc);
                acc = fmaf(bf_hi(d0.y), c0.w, acc);
                acc = fmaf(bf_lo(d0.z), c1.x, acc);
                acc = fmaf(bf_hi(d0.z), c1.y, acc);
                acc = fmaf(bf_lo(d0.w), c1.z, acc);
                acc = fmaf(bf_hi(d0.w), c1.w, acc);
                acc = fmaf(bf_lo(d1.x), c2.x, acc);
                acc = fmaf(bf_hi(d1.x), c2.y, acc);
                acc = fmaf(bf_lo(d1.y), c2.z, acc);
                acc = fmaf(bf_hi(d1.y), c2.w, acc);
                acc = fmaf(bf_lo(d1.z), c3.x, acc);
                acc = fmaf(bf_hi(d1.z), c3.y, acc);
                acc = fmaf(bf_lo(d1.w), c3.z, acc);
                acc = fmaf(bf_hi(d1.w), c3.w, acc);
                srt_f[(w * NOD + od) * 33 + i] = acc;
            }
            __builtin_amdgcn_wave_barrier();
#pragma unroll
            for (int od = 0; od < NOD; ++od)
                lg[od] += srt_f[(w * NOD + od) * 33 + iown];
            __builtin_amdgcn_wave_barrier();
        }
    }

    // ---- output: float4 across the block's 4 consecutive pixels ----
    __syncthreads();
    if (tid < NK) {
        const float4 v = make_float4(sact_f[0 * 164 + tid], sact_f[1 * 164 + tid],
                                     sact_f[2 * 164 + tid], sact_f[3 * 164 + tid]);
        *reinterpret_cast<float4*>(out + ((size_t)b * NK + tid) * NHW + hw0) = v;
    }
}

extern "C" void kernel_launch(void* const* d_in, const int* in_sizes, int n_in,
                              void* d_out, int out_size, void* d_ws, size_t ws_size,
                              hipStream_t stream) {
    const float* x      = (const float*)d_in[0];
    const float* weight = (const float*)d_in[1];
    const float* bias   = (const float*)d_in[2];
    float* out          = (float*)d_out;

    capsule_fused_kernel<<<NROWS / 4, 256, 0, stream>>>(x, weight, bias, out);
}